// Round 4
// baseline (1096.835 us; speedup 1.0000x reference)
//
#include <hip/hip_runtime.h>
#include <hip/hip_cooperative_groups.h>

namespace cg = cooperative_groups;

typedef unsigned int uint;
typedef unsigned short ushort;

typedef float f32x4 __attribute__((ext_vector_type(4)));
typedef __bf16 bf16x8 __attribute__((ext_vector_type(8)));

__device__ __forceinline__ float bf2f(uint bits) {
  return __uint_as_float(bits << 16);
}
__device__ __forceinline__ ushort f2bf(float f) {
  uint u = __float_as_uint(f);
  u += 0x7fffu + ((u >> 16) & 1u);   // round-to-nearest-even
  return (ushort)(u >> 16);
}
__device__ __forceinline__ uint pack2(float a, float b) {
  return (uint)f2bf(a) | ((uint)f2bf(b) << 16);
}
__device__ __forceinline__ int xcd_id() {
  int x;
  asm volatile("s_getreg_b32 %0, hwreg(HW_REG_XCC_ID, 0, 4)" : "=s"(x));
  return x & 7;
}
__device__ __forceinline__ void wg_inc(int* p) {
  __hip_atomic_fetch_add(p, 1, __ATOMIC_RELAXED, __HIP_MEMORY_SCOPE_WORKGROUP);
}

// ---------- dtype probe: bf16-packed vs float32 ----------
__global__ void detect_k(const uint* __restrict__ xu, int* __restrict__ flag) {
  uint u = xu[threadIdx.x];
  uint e = (u >> 7) & 0xFFu;
  unsigned long long m = __ballot(e >= 116u && e <= 130u);
  if (threadIdx.x == 0) flag[0] = (__builtin_popcountll(m) >= 32) ? 1 : 0;
}

// ---------- cooperative CSR build ----------
// One dispatch: per-XCD-replicated histograms with WORKGROUP-scope atomics
// (RMW resolves in the local XCD L2, not at the fabric coherence point).
// Blocks keep their CU (and thus XCD) for the whole kernel, so the phase-1
// per-XCD counts exactly describe phase-5's per-XCD bucket partition under
// ANY workgroup->XCD placement (G16-safe). __threadfence() around grid.sync
// = agent release/acquire (L2 writeback + invalidate) for cross-XCD reads.
__global__ __launch_bounds__(256, 2) void csr_coop(
    const int* __restrict__ src, const int* __restrict__ dst,
    int* __restrict__ h_out, int* __restrict__ h_in,   // [8][n], pre-zeroed
    float* __restrict__ ns, float* __restrict__ nd,
    int* __restrict__ deg_in, int* __restrict__ tmp, int* __restrict__ bsums,
    int* __restrict__ row_off, int* __restrict__ cursor, int* __restrict__ csr,
    int n, int E, int nvb) {
  cg::grid_group grid = cg::this_grid();
  __shared__ int lds[256];
  const int tid = threadIdx.x;
  const int nb = gridDim.x;
  const int gstride = nb * 256;
  const int xcc = xcd_id();
  int* ho = h_out + xcc * n;
  int* hi = h_in + xcc * n;

  // phase 1: replicated degree count, XCD-local atomics
  for (int e = blockIdx.x * 256 + tid; e < E; e += gstride) {
    wg_inc(&ho[src[e]]);
    wg_inc(&hi[dst[e]]);
  }
  __threadfence();
  grid.sync();
  __threadfence();

  // phase 2: reduce replicas -> norms + deg_in, and 1024-tile inclusive scan
  for (int vb = blockIdx.x; vb < nvb; vb += nb) {
    int idx = vb * 1024 + tid * 4;
    int v[4];
    int s = 0;
#pragma unroll
    for (int j = 0; j < 4; ++j) {
      int i = idx + j;
      int di = 0;
      if (i < n) {
        int dl = 0;
#pragma unroll
        for (int g = 0; g < 8; ++g) {
          di += h_in[g * n + i];
          dl += h_out[g * n + i];
        }
        ns[i] = rsqrtf(fmaxf((float)dl, 1.f));
        nd[i] = rsqrtf(fmaxf((float)di, 1.f));
        deg_in[i] = di;
      }
      v[j] = di;
      s += v[j];
    }
    lds[tid] = s;
    __syncthreads();
    for (int off = 1; off < 256; off <<= 1) {
      int t_ = 0;
      if (tid >= off) t_ = lds[tid - off];
      __syncthreads();
      if (tid >= off) lds[tid] += t_;
      __syncthreads();
    }
    int run = (tid > 0) ? lds[tid - 1] : 0;
#pragma unroll
    for (int j = 0; j < 4; ++j) {
      run += v[j];
      if (idx + j < n) tmp[idx + j] = run;
    }
    if (tid == 255) bsums[vb] = lds[255];
    __syncthreads();
  }
  __threadfence();
  grid.sync();
  __threadfence();

  // phase 3: serial scan of tile sums (nvb ~ 98)
  if (blockIdx.x == 0 && tid == 0) {
    int run = 0;
    for (int i = 0; i < nvb; ++i) { int t_ = bsums[i]; bsums[i] = run; run += t_; }
  }
  __threadfence();
  grid.sync();
  __threadfence();

  // phase 4: row_off + per-(xcd,row) cursor bases
  for (int i = blockIdx.x * 256 + tid; i < n; i += gstride) {
    int incl = tmp[i] + bsums[i >> 10];
    row_off[i + 1] = incl;
    if (i == 0) row_off[0] = 0;
    int c = incl - deg_in[i];   // exclusive start of row i
#pragma unroll
    for (int g = 0; g < 8; ++g) {
      cursor[g * n + i] = c;
      c += h_in[g * n + i];
    }
  }
  __threadfence();
  grid.sync();
  __threadfence();

  // phase 5: bucket edges (same block -> same edges & same XCD as phase 1)
  int* cur = cursor + xcc * n;
  for (int e = blockIdx.x * 256 + tid; e < E; e += gstride) {
    int slot = __hip_atomic_fetch_add(&cur[dst[e]], 1, __ATOMIC_RELAXED,
                                      __HIP_MEMORY_SCOPE_WORKGROUP);
    csr[slot] = src[e];
  }
}

// ---------- W fragment pre-swizzle (B-operand layout, 16x16x32 bf16) ----------
__global__ void wswz(const void* __restrict__ W1p, const void* __restrict__ W2p,
                     ushort* __restrict__ wf1, ushort* __restrict__ wf2,
                     const int* __restrict__ flagp) {
  int bf = *flagp;
  int tid = blockIdx.x * blockDim.x + threadIdx.x;  // 0..4095
  const void* W = (tid & 2048) ? W2p : W1p;
  ushort* wf = (tid & 2048) ? wf2 : wf1;
  int chunk = tid & 2047;
  int n0 = chunk & 15;
  int quad = (chunk >> 4) & 3;
  int kk = (chunk >> 6) & 3;
  int c = chunk >> 8;
  int col = c * 16 + n0;
#pragma unroll
  for (int j = 0; j < 8; ++j) {
    int idx = (kk * 32 + quad * 8 + j) * 128 + col;
    ushort v = bf ? ((const ushort*)W)[idx] : f2bf(((const float*)W)[idx]);
    wf[chunk * 8 + j] = v;
  }
}

// ---------- GEMM: t[r][:] = (x[r][:] @ W) * ns[r] ----------
__global__ __launch_bounds__(256) void gemm_ns(const void* __restrict__ xp,
                                               const ushort* __restrict__ wf,
                                               const float* __restrict__ ns,
                                               ushort* __restrict__ t,
                                               const int* __restrict__ flagp,
                                               int forced_bf, int n) {
  __shared__ __align__(16) ushort Xs[64][136];
  __shared__ __align__(16) ushort Ws[16384];
  const int tid = threadIdx.x;
  const int rowbase = blockIdx.x * 64;
  const int eff_bf = forced_bf | *flagp;

#pragma unroll
  for (int i = 0; i < 8; ++i)
    ((uint4*)Ws)[i * 256 + tid] = ((const uint4*)wf)[i * 256 + tid];

#pragma unroll
  for (int i = 0; i < 4; ++i) {
    int cid = i * 256 + tid;       // 1024 chunks of 8 elements
    int r = cid >> 4;
    int co = (cid & 15) << 3;
    int gr = rowbase + r;
    uint4 v = {0u, 0u, 0u, 0u};
    if (gr < n) {
      if (eff_bf) {
        v = *(const uint4*)((const ushort*)xp + (size_t)gr * 128 + co);
      } else {
        const float* xf = (const float*)xp + (size_t)gr * 128 + co;
        float4 f0 = *(const float4*)xf;
        float4 f1 = *(const float4*)(xf + 4);
        v.x = pack2(f0.x, f0.y); v.y = pack2(f0.z, f0.w);
        v.z = pack2(f1.x, f1.y); v.w = pack2(f1.z, f1.w);
      }
    }
    *(uint4*)&Xs[r][co] = v;
  }
  __syncthreads();

  const int w = tid >> 6;
  const int lane = tid & 63;
  const int m = lane & 15;
  const int quad = lane >> 4;

  bf16x8 a[4];
#pragma unroll
  for (int kk = 0; kk < 4; ++kk)
    a[kk] = *(const bf16x8*)&Xs[w * 16 + m][kk * 32 + quad * 8];

  int grs[4];
  float nsv[4];
#pragma unroll
  for (int reg = 0; reg < 4; ++reg) {
    int gr = rowbase + w * 16 + quad * 4 + reg;
    grs[reg] = gr;
    nsv[reg] = (gr < n) ? ns[gr] : 0.f;
  }

#pragma unroll
  for (int c = 0; c < 8; ++c) {
    f32x4 acc = {0.f, 0.f, 0.f, 0.f};
#pragma unroll
    for (int kk = 0; kk < 4; ++kk) {
      bf16x8 b = *(const bf16x8*)&Ws[(((c * 4 + kk) * 4 + quad) * 16 + m) * 8];
      acc = __builtin_amdgcn_mfma_f32_16x16x32_bf16(a[kk], b, acc, 0, 0, 0);
    }
    int col = c * 16 + m;
#pragma unroll
    for (int reg = 0; reg < 4; ++reg) {
      if (grs[reg] < n)
        t[(size_t)grs[reg] * 128 + col] = f2bf(acc[reg] * nsv[reg]);
    }
  }
}

// ---------- aggregation ----------
__global__ __launch_bounds__(256) void agg_k(const uint* __restrict__ tu,
                                             const int* __restrict__ row_off,
                                             const int* __restrict__ csr,
                                             const float* __restrict__ nd,
                                             const void* __restrict__ bp,
                                             void* __restrict__ outp,
                                             int relu, int is_final,
                                             const int* __restrict__ flagp, int n) {
  int node = (blockIdx.x * 256 + threadIdx.x) >> 6;  // one wave per node
  int lane = threadIdx.x & 63;
  int bf = *flagp;
  if (node >= n) return;
  int e0 = row_off[node], e1 = row_off[node + 1];
  float a0 = 0.f, a1 = 0.f;
  int e = e0;
  for (; e + 4 <= e1; e += 4) {
    int s0 = csr[e], s1 = csr[e + 1], s2 = csr[e + 2], s3 = csr[e + 3];
    uint v0 = tu[(size_t)s0 * 64 + lane];
    uint v1 = tu[(size_t)s1 * 64 + lane];
    uint v2 = tu[(size_t)s2 * 64 + lane];
    uint v3 = tu[(size_t)s3 * 64 + lane];
    a0 += (bf2f(v0 & 0xffffu) + bf2f(v1 & 0xffffu)) + (bf2f(v2 & 0xffffu) + bf2f(v3 & 0xffffu));
    a1 += (bf2f(v0 >> 16) + bf2f(v1 >> 16)) + (bf2f(v2 >> 16) + bf2f(v3 >> 16));
  }
  for (; e < e1; ++e) {
    int s = csr[e];
    uint v = tu[(size_t)s * 64 + lane];
    a0 += bf2f(v & 0xffffu);
    a1 += bf2f(v >> 16);
  }
  float bias0, bias1;
  if (bf) {
    uint bv = ((const uint*)bp)[lane];
    bias0 = bf2f(bv & 0xffffu);
    bias1 = bf2f(bv >> 16);
  } else {
    const float* b32 = (const float*)bp;
    bias0 = b32[2 * lane];
    bias1 = b32[2 * lane + 1];
  }
  float nrm = nd[node];
  float o0 = a0 * nrm + bias0;
  float o1 = a1 * nrm + bias1;
  if (relu) { o0 = fmaxf(o0, 0.f); o1 = fmaxf(o1, 0.f); }
  if (!is_final || bf) {
    ((uint*)outp)[(size_t)node * 64 + lane] = pack2(o0, o1);
  } else {
    ((float2*)outp)[(size_t)node * 64 + lane] = make_float2(o0, o1);
  }
}

extern "C" void kernel_launch(void* const* d_in, const int* in_sizes, int n_in,
                              void* d_out, int out_size, void* d_ws, size_t ws_size,
                              hipStream_t stream) {
  int n = in_sizes[0] / 128;   // 100000 nodes
  int E = in_sizes[1];         // 1600000 edges

  const void* feat = d_in[0];
  const int* src = (const int*)d_in[1];
  const int* dst = (const int*)d_in[2];
  const void* W1 = d_in[3];
  const void* b1 = d_in[4];
  const void* W2 = d_in[5];
  const void* b2 = d_in[6];

  // workspace carve-up (256B-aligned slabs); ~34 MB total
  char* p = (char*)d_ws;
  auto alloc = [&](size_t bytes) -> char* {
    char* q = p;
    p += (bytes + 255) & ~(size_t)255;
    return q;
  };
  int* flag = (int*)alloc(256);
  // region A: t (25.6 MB, live from gemm1 on) aliases CSR-build scratch
  // (26n ints = 10.4 MB, dead before gemm1 launches)
  ushort* t = (ushort*)alloc((size_t)n * 128 * 2);
  int* h_out = (int*)t;            // [8][n]
  int* h_in = h_out + 8 * n;       // [8][n]
  int* cursor = h_in + 8 * n;      // [8][n]
  int* deg_in = cursor + 8 * n;    // [n]
  int* tmp = deg_in + n;           // [n]
  int* bsums = tmp + n;            // 256
  // persistent slabs
  ushort* wf1 = (ushort*)alloc(16384 * 2);
  ushort* wf2 = (ushort*)alloc(16384 * 2);
  float* ns = (float*)alloc((size_t)n * 4);
  float* nd = (float*)alloc((size_t)n * 4);
  int* row_off = (int*)alloc((size_t)(n + 1) * 4);
  int* csr = (int*)alloc((size_t)E * 4);

  // layer-1 intermediate lives in d_out (internal bf16), overwritten by final
  ushort* y1 = (ushort*)d_out;

  const int TB = 256;
  const int gGemm = (n + 63) / 64;
  const int gAgg = (n + 3) / 4;
  int nvb = (n + 1023) / 1024;

  detect_k<<<1, 64, 0, stream>>>((const uint*)feat, flag);
  hipMemsetAsync(h_out, 0, (size_t)16 * n * 4, stream);  // h_out + h_in

  {
    const int* src_ = src;
    const int* dst_ = dst;
    void* args[] = {(void*)&src_, (void*)&dst_, (void*)&h_out, (void*)&h_in,
                    (void*)&ns, (void*)&nd, (void*)&deg_in, (void*)&tmp,
                    (void*)&bsums, (void*)&row_off, (void*)&cursor, (void*)&csr,
                    (void*)&n, (void*)&E, (void*)&nvb};
    hipLaunchCooperativeKernel((const void*)csr_coop, dim3(512), dim3(TB),
                               args, 0, stream);
  }

  wswz<<<16, TB, 0, stream>>>(W1, W2, wf1, wf2, flag);

  // layer 1
  gemm_ns<<<gGemm, TB, 0, stream>>>(feat, wf1, ns, t, flag, 0, n);
  agg_k<<<gAgg, TB, 0, stream>>>((const uint*)t, row_off, csr, nd, b1,
                                 (void*)y1, 1, 0, flag, n);
  // layer 2 (y1 is internal bf16 regardless of input dtype)
  gemm_ns<<<gGemm, TB, 0, stream>>>((const void*)y1, wf2, ns, t, flag, 1, n);
  agg_k<<<gAgg, TB, 0, stream>>>((const uint*)t, row_off, csr, nd, b2,
                                 d_out, 0, 1, flag, n);
}

// Round 5
// 387.637 us; speedup vs baseline: 2.8295x; 2.8295x over previous
//
#include <hip/hip_runtime.h>

typedef unsigned int uint;
typedef unsigned short ushort;

typedef float f32x4 __attribute__((ext_vector_type(4)));
typedef __bf16 bf16x8 __attribute__((ext_vector_type(8)));

__device__ __forceinline__ float bf2f(uint bits) {
  return __uint_as_float(bits << 16);
}
__device__ __forceinline__ ushort f2bf(float f) {
  uint u = __float_as_uint(f);
  u += 0x7fffu + ((u >> 16) & 1u);   // round-to-nearest-even
  return (ushort)(u >> 16);
}
__device__ __forceinline__ uint pack2(float a, float b) {
  return (uint)f2bf(a) | ((uint)f2bf(b) << 16);
}

// inclusive block scan of per-thread values over 256 threads (ts = 256-slot LDS)
__device__ __forceinline__ void block_scan256(int v, int* ts, int tid) {
  ts[tid] = v;
  __syncthreads();
  for (int off = 1; off < 256; off <<= 1) {
    int t_ = 0;
    if (tid >= off) t_ = ts[tid - off];
    __syncthreads();
    if (tid >= off) ts[tid] += t_;
    __syncthreads();
  }
}

// ---------- dtype probe: bf16-packed vs float32 ----------
__global__ void detect_k(const uint* __restrict__ xu, int* __restrict__ flag) {
  uint u = xu[threadIdx.x];
  uint e = (u >> 7) & 0xFFu;
  unsigned long long m = __ballot(e >= 116u && e <= 130u);
  if (threadIdx.x == 0) flag[0] = (__builtin_popcountll(m) >= 32) ? 1 : 0;
}

// ================= atomic-free CSR build (two-level counting sort) ==========
// Coarse bucket = 512-node range (B = ceil(n/512) buckets, B <= 1024).
// All histogram/cursor conflicts live in LDS; all global I/O is coalesced.

// K1: per-chunk coarse histograms for BOTH keys (dst and src), one edge pass.
__global__ __launch_bounds__(256) void part_hist(
    const int* __restrict__ src, const int* __restrict__ dst,
    int* __restrict__ gh_d, int* __restrict__ gh_s,
    int B, int P, int nIter, int E) {
  __shared__ int hd[1024], hs[1024];
  const int tid = threadIdx.x, blk = blockIdx.x;
  for (int i = tid; i < B; i += 256) { hd[i] = 0; hs[i] = 0; }
  __syncthreads();
  int e0 = blk * (nIter << 8);
  for (int i = 0; i < nIter; ++i) {
    int e = e0 + (i << 8) + tid;
    if (e < E) {
      atomicAdd(&hd[dst[e] >> 9], 1);
      atomicAdd(&hs[src[e] >> 9], 1);
    }
  }
  __syncthreads();
  for (int i = tid; i < B; i += 256) {
    gh_d[i * P + blk] = hd[i];
    gh_s[i * P + blk] = hs[i];
  }
}

// K2: per-(key,bucket) exclusive scan over the P chunk-counts, in place.
__global__ __launch_bounds__(256) void part_scan(
    int* __restrict__ gh_d, int* __restrict__ gh_s,
    int* __restrict__ btot, int B, int P) {
  __shared__ int ts[256];
  const int tid = threadIdx.x;
  const int id = blockIdx.x;          // [0,2B): dst buckets then src buckets
  int* gh = (id < B) ? gh_d : gh_s;
  const int b = (id < B) ? id : id - B;
  int v0 = (2 * tid < P) ? gh[b * P + 2 * tid] : 0;
  int v1 = (2 * tid + 1 < P) ? gh[b * P + 2 * tid + 1] : 0;
  block_scan256(v0 + v1, ts, tid);
  int excl = (tid > 0) ? ts[tid - 1] : 0;
  if (2 * tid < P) gh[b * P + 2 * tid] = excl;
  if (2 * tid + 1 < P) gh[b * P + 2 * tid + 1] = excl + v0;
  if (tid == 255) btot[id] = ts[255];
}

// K3: serial scan of bucket totals (2B <= 2048 values — trivial).
__global__ void bucket_scan(const int* __restrict__ btot,
                            int* __restrict__ bb_d, int* __restrict__ bb_s, int B) {
  if (threadIdx.x == 0) {
    int run = 0;
    for (int i = 0; i < B; ++i) { bb_d[i] = run; run += btot[i]; }
    bb_d[B] = run;
    run = 0;
    for (int i = 0; i < B; ++i) { bb_s[i] = run; run += btot[B + i]; }
    bb_s[B] = run;
  }
}

// K4: scatter edges into bucket-partitioned buffers (LDS cursors; runs of
// ~chunk/B consecutive slots per bucket -> near-full-line writes).
// pack: src (17b) | dstlocal (9b) << 17   [requires n <= 131072]
__global__ __launch_bounds__(256) void part_scat(
    const int* __restrict__ src, const int* __restrict__ dst,
    const int* __restrict__ gh_d, const int* __restrict__ gh_s,
    const int* __restrict__ bb_d, const int* __restrict__ bb_s,
    uint* __restrict__ ebuf_d, ushort* __restrict__ ebuf_s,
    int B, int P, int nIter, int E) {
  __shared__ int cd[1024], cs[1024];
  const int tid = threadIdx.x, blk = blockIdx.x;
  for (int i = tid; i < B; i += 256) {
    cd[i] = bb_d[i] + gh_d[i * P + blk];
    cs[i] = bb_s[i] + gh_s[i * P + blk];
  }
  __syncthreads();
  int e0 = blk * (nIter << 8);
  for (int i = 0; i < nIter; ++i) {
    int e = e0 + (i << 8) + tid;
    if (e < E) {
      int s = src[e], d = dst[e];
      int pd = atomicAdd(&cd[d >> 9], 1);
      ebuf_d[pd] = (uint)s | ((uint)(d & 511) << 17);
      int ps = atomicAdd(&cs[s >> 9], 1);
      ebuf_s[ps] = (ushort)(s & 511);
    }
  }
}

// K5: per-bucket fine pass. dst side: 512-bin LDS histogram + scan ->
// row_off/nd/csr (nodes are bucket-exclusive, so row_off is direct — no
// global node scan). src side: histogram -> ns.
__global__ __launch_bounds__(256) void fine_k(
    const uint* __restrict__ ebuf_d, const ushort* __restrict__ ebuf_s,
    const int* __restrict__ bb_d, const int* __restrict__ bb_s,
    int* __restrict__ row_off, int* __restrict__ csr,
    float* __restrict__ ns, float* __restrict__ nd,
    int B, int n, int E) {
  __shared__ int cnt[512];
  __shared__ int off[512];
  __shared__ int ts[256];
  const int tid = threadIdx.x;
  const int id = blockIdx.x;          // [0,2B)
  for (int i = tid; i < 512; i += 256) cnt[i] = 0;
  __syncthreads();
  if (id < B) {
    const int b = id;
    const int lo = bb_d[b], hi = bb_d[b + 1];
    for (int e = lo + tid; e < hi; e += 256)
      atomicAdd(&cnt[(ebuf_d[e] >> 17) & 511], 1);
    __syncthreads();
    int c0 = cnt[2 * tid], c1 = cnt[2 * tid + 1];
    block_scan256(c0 + c1, ts, tid);
    int excl = (tid > 0) ? ts[tid - 1] : 0;
    off[2 * tid] = excl;
    off[2 * tid + 1] = excl + c0;
    __syncthreads();
    for (int i = tid; i < 512; i += 256) {
      int g = b * 512 + i;
      if (g < n) {
        row_off[g] = lo + off[i];
        nd[g] = rsqrtf(fmaxf((float)cnt[i], 1.f));
      }
    }
    if (id == 0 && tid == 0) row_off[n] = E;
    __syncthreads();
    for (int i = tid; i < 512; i += 256) cnt[i] = off[i];  // cnt -> cursor
    __syncthreads();
    for (int e = lo + tid; e < hi; e += 256) {
      uint v = ebuf_d[e];
      int l = (v >> 17) & 511;
      int slot = atomicAdd(&cnt[l], 1);
      csr[lo + slot] = (int)(v & 0x1FFFFu);   // 4B-random within 25KB window:
    }                                          // L2 write-combines to full lines
  } else {
    const int b = id - B;
    const int lo = bb_s[b], hi = bb_s[b + 1];
    for (int e = lo + tid; e < hi; e += 256)
      atomicAdd(&cnt[ebuf_s[e]], 1);
    __syncthreads();
    for (int i = tid; i < 512; i += 256) {
      int g = b * 512 + i;
      if (g < n) ns[g] = rsqrtf(fmaxf((float)cnt[i], 1.f));
    }
  }
}

// ---------- W fragment pre-swizzle (B-operand layout, 16x16x32 bf16) ----------
__global__ void wswz(const void* __restrict__ W1p, const void* __restrict__ W2p,
                     ushort* __restrict__ wf1, ushort* __restrict__ wf2,
                     const int* __restrict__ flagp) {
  int bf = *flagp;
  int tid = blockIdx.x * blockDim.x + threadIdx.x;  // 0..4095
  const void* W = (tid & 2048) ? W2p : W1p;
  ushort* wf = (tid & 2048) ? wf2 : wf1;
  int chunk = tid & 2047;
  int n0 = chunk & 15;
  int quad = (chunk >> 4) & 3;
  int kk = (chunk >> 6) & 3;
  int c = chunk >> 8;
  int col = c * 16 + n0;
#pragma unroll
  for (int j = 0; j < 8; ++j) {
    int idx = (kk * 32 + quad * 8 + j) * 128 + col;
    ushort v = bf ? ((const ushort*)W)[idx] : f2bf(((const float*)W)[idx]);
    wf[chunk * 8 + j] = v;
  }
}

// ---------- GEMM: t[r][:] = (x[r][:] @ W) * ns[r] ----------
__global__ __launch_bounds__(256) void gemm_ns(const void* __restrict__ xp,
                                               const ushort* __restrict__ wf,
                                               const float* __restrict__ ns,
                                               ushort* __restrict__ t,
                                               const int* __restrict__ flagp,
                                               int forced_bf, int n) {
  __shared__ __align__(16) ushort Xs[64][136];
  __shared__ __align__(16) ushort Ws[16384];
  const int tid = threadIdx.x;
  const int rowbase = blockIdx.x * 64;
  const int eff_bf = forced_bf | *flagp;

#pragma unroll
  for (int i = 0; i < 8; ++i)
    ((uint4*)Ws)[i * 256 + tid] = ((const uint4*)wf)[i * 256 + tid];

#pragma unroll
  for (int i = 0; i < 4; ++i) {
    int cid = i * 256 + tid;       // 1024 chunks of 8 elements
    int r = cid >> 4;
    int co = (cid & 15) << 3;
    int gr = rowbase + r;
    uint4 v = {0u, 0u, 0u, 0u};
    if (gr < n) {
      if (eff_bf) {
        v = *(const uint4*)((const ushort*)xp + (size_t)gr * 128 + co);
      } else {
        const float* xf = (const float*)xp + (size_t)gr * 128 + co;
        float4 f0 = *(const float4*)xf;
        float4 f1 = *(const float4*)(xf + 4);
        v.x = pack2(f0.x, f0.y); v.y = pack2(f0.z, f0.w);
        v.z = pack2(f1.x, f1.y); v.w = pack2(f1.z, f1.w);
      }
    }
    *(uint4*)&Xs[r][co] = v;
  }
  __syncthreads();

  const int w = tid >> 6;
  const int lane = tid & 63;
  const int m = lane & 15;
  const int quad = lane >> 4;

  bf16x8 a[4];
#pragma unroll
  for (int kk = 0; kk < 4; ++kk)
    a[kk] = *(const bf16x8*)&Xs[w * 16 + m][kk * 32 + quad * 8];

  int grs[4];
  float nsv[4];
#pragma unroll
  for (int reg = 0; reg < 4; ++reg) {
    int gr = rowbase + w * 16 + quad * 4 + reg;
    grs[reg] = gr;
    nsv[reg] = (gr < n) ? ns[gr] : 0.f;
  }

#pragma unroll
  for (int c = 0; c < 8; ++c) {
    f32x4 acc = {0.f, 0.f, 0.f, 0.f};
#pragma unroll
    for (int kk = 0; kk < 4; ++kk) {
      bf16x8 b = *(const bf16x8*)&Ws[(((c * 4 + kk) * 4 + quad) * 16 + m) * 8];
      acc = __builtin_amdgcn_mfma_f32_16x16x32_bf16(a[kk], b, acc, 0, 0, 0);
    }
    int col = c * 16 + m;
#pragma unroll
    for (int reg = 0; reg < 4; ++reg) {
      if (grs[reg] < n)
        t[(size_t)grs[reg] * 128 + col] = f2bf(acc[reg] * nsv[reg]);
    }
  }
}

// ---------- aggregation ----------
__global__ __launch_bounds__(256) void agg_k(const uint* __restrict__ tu,
                                             const int* __restrict__ row_off,
                                             const int* __restrict__ csr,
                                             const float* __restrict__ nd,
                                             const void* __restrict__ bp,
                                             void* __restrict__ outp,
                                             int relu, int is_final,
                                             const int* __restrict__ flagp, int n) {
  int node = (blockIdx.x * 256 + threadIdx.x) >> 6;  // one wave per node
  int lane = threadIdx.x & 63;
  int bf = *flagp;
  if (node >= n) return;
  int e0 = row_off[node], e1 = row_off[node + 1];
  float a0 = 0.f, a1 = 0.f;
  int e = e0;
  for (; e + 4 <= e1; e += 4) {
    int s0 = csr[e], s1 = csr[e + 1], s2 = csr[e + 2], s3 = csr[e + 3];
    uint v0 = tu[(size_t)s0 * 64 + lane];
    uint v1 = tu[(size_t)s1 * 64 + lane];
    uint v2 = tu[(size_t)s2 * 64 + lane];
    uint v3 = tu[(size_t)s3 * 64 + lane];
    a0 += (bf2f(v0 & 0xffffu) + bf2f(v1 & 0xffffu)) + (bf2f(v2 & 0xffffu) + bf2f(v3 & 0xffffu));
    a1 += (bf2f(v0 >> 16) + bf2f(v1 >> 16)) + (bf2f(v2 >> 16) + bf2f(v3 >> 16));
  }
  for (; e < e1; ++e) {
    int s = csr[e];
    uint v = tu[(size_t)s * 64 + lane];
    a0 += bf2f(v & 0xffffu);
    a1 += bf2f(v >> 16);
  }
  float bias0, bias1;
  if (bf) {
    uint bv = ((const uint*)bp)[lane];
    bias0 = bf2f(bv & 0xffffu);
    bias1 = bf2f(bv >> 16);
  } else {
    const float* b32 = (const float*)bp;
    bias0 = b32[2 * lane];
    bias1 = b32[2 * lane + 1];
  }
  float nrm = nd[node];
  float o0 = a0 * nrm + bias0;
  float o1 = a1 * nrm + bias1;
  if (relu) { o0 = fmaxf(o0, 0.f); o1 = fmaxf(o1, 0.f); }
  if (!is_final || bf) {
    ((uint*)outp)[(size_t)node * 64 + lane] = pack2(o0, o1);
  } else {
    ((float2*)outp)[(size_t)node * 64 + lane] = make_float2(o0, o1);
  }
}

extern "C" void kernel_launch(void* const* d_in, const int* in_sizes, int n_in,
                              void* d_out, int out_size, void* d_ws, size_t ws_size,
                              hipStream_t stream) {
  int n = in_sizes[0] / 128;   // 100000 nodes
  int E = in_sizes[1];         // 1600000 edges

  const void* feat = d_in[0];
  const int* src = (const int*)d_in[1];
  const int* dst = (const int*)d_in[2];
  const void* W1 = d_in[3];
  const void* b1 = d_in[4];
  const void* W2 = d_in[5];
  const void* b2 = d_in[6];

  // sort geometry
  const int B = (n + 511) >> 9;          // coarse buckets (196 for n=100k)
  int chunk = 4096;
  int P = (E + chunk - 1) / chunk;
  if (P > 512) {
    chunk = (((E + 511) / 512) + 4095) / 4096 * 4096;
    P = (E + chunk - 1) / chunk;
  }
  const int nIter = chunk >> 8;

  // workspace carve-up (256B-aligned slabs); ~33 MB total
  char* p = (char*)d_ws;
  auto alloc = [&](size_t bytes) -> char* {
    char* q = p;
    p += (bytes + 255) & ~(size_t)255;
    return q;
  };
  int* flag = (int*)alloc(256);
  // region A: t (25.6 MB, live from gemm1 on) aliases sort scratch (dead by then)
  ushort* t = (ushort*)alloc((size_t)n * 128 * 2);
  {
    char* q = (char*)t;
    auto suballoc = [&](size_t bytes) -> char* {
      char* r = q;
      q += (bytes + 255) & ~(size_t)255;
      return r;
    };
    (void)suballoc;
  }
  uint* ebuf_d = (uint*)t;                                  // E*4
  ushort* ebuf_s = (ushort*)(ebuf_d + E);                   // E*2
  int* gh_d = (int*)(ebuf_s + ((E + 1) & ~1));              // B*P*4
  int* gh_s = gh_d + B * P;                                 // B*P*4
  int* btot = gh_s + B * P;                                 // 2B
  int* bb_d = btot + 2 * B;                                 // B+1
  int* bb_s = bb_d + (B + 1);                               // B+1
  // (sort scratch total ~13 MB < 25.6 MB slab)
  // persistent slabs
  ushort* wf1 = (ushort*)alloc(16384 * 2);
  ushort* wf2 = (ushort*)alloc(16384 * 2);
  float* ns = (float*)alloc((size_t)n * 4);
  float* nd = (float*)alloc((size_t)n * 4);
  int* row_off = (int*)alloc((size_t)(n + 1) * 4);
  int* csr = (int*)alloc((size_t)E * 4);

  // layer-1 intermediate lives in d_out (internal bf16), overwritten by final
  ushort* y1 = (ushort*)d_out;

  const int TB = 256;
  const int gGemm = (n + 63) / 64;
  const int gAgg = (n + 3) / 4;

  detect_k<<<1, 64, 0, stream>>>((const uint*)feat, flag);
  part_hist<<<P, TB, 0, stream>>>(src, dst, gh_d, gh_s, B, P, nIter, E);
  part_scan<<<2 * B, TB, 0, stream>>>(gh_d, gh_s, btot, B, P);
  bucket_scan<<<1, 64, 0, stream>>>(btot, bb_d, bb_s, B);
  part_scat<<<P, TB, 0, stream>>>(src, dst, gh_d, gh_s, bb_d, bb_s,
                                  ebuf_d, ebuf_s, B, P, nIter, E);
  fine_k<<<2 * B, TB, 0, stream>>>(ebuf_d, ebuf_s, bb_d, bb_s,
                                   row_off, csr, ns, nd, B, n, E);
  wswz<<<16, TB, 0, stream>>>(W1, W2, wf1, wf2, flag);

  // layer 1
  gemm_ns<<<gGemm, TB, 0, stream>>>(feat, wf1, ns, t, flag, 0, n);
  agg_k<<<gAgg, TB, 0, stream>>>((const uint*)t, row_off, csr, nd, b1,
                                 (void*)y1, 1, 0, flag, n);
  // layer 2 (y1 is internal bf16 regardless of input dtype)
  gemm_ns<<<gGemm, TB, 0, stream>>>((const void*)y1, wf2, ns, t, flag, 1, n);
  agg_k<<<gAgg, TB, 0, stream>>>((const uint*)t, row_off, csr, nd, b2,
                                 d_out, 0, 1, flag, n);
}